// Round 19
// baseline (467.119 us; speedup 1.0000x reference)
//
#include <hip/hip_runtime.h>
#include <cstdint>

typedef unsigned short u16;
typedef __attribute__((ext_vector_type(8))) short bf16x8;
typedef __attribute__((ext_vector_type(4))) float f32x4;

#define DEV static __device__ __forceinline__
#define AS1 __attribute__((address_space(1)))
#define AS3 __attribute__((address_space(3)))

static constexpr int Bb = 4, Tt = 512, Nn = 1024, Dd = 1024, Hh = 16;
static constexpr float NEGV = -10000.0f;

DEV u16 f2bf(float f) {
  unsigned int u = __builtin_bit_cast(unsigned int, f);
  u += 0x7fffu + ((u >> 16) & 1u);
  return (u16)(u >> 16);
}
DEV float bf2f(u16 s) {
  unsigned int u = ((unsigned int)s) << 16;
  return __builtin_bit_cast(float, u);
}
DEV f32x4 mfma16(bf16x8 a, bf16x8 b, f32x4 c) {
  return __builtin_amdgcn_mfma_f32_16x16x32_bf16(a, b, c, 0, 0, 0);
}
DEV void gload16(const u16* g, u16* lds) {
  __builtin_amdgcn_global_load_lds((AS1 const unsigned int*)g, (AS3 unsigned int*)lds, 16, 0, 0);
}
// chunked XCD swizzle; requires nwg % 8 == 0
DEV int swz8(int wg, int nwg) { const int c = nwg >> 3; return (wg & 7) * c + (wg >> 3); }

// ---------------- batched transpose+cast: 12 weights in ONE launch ----------------
struct TrDesc { const float* s; u16* d; int R, C, t0; };
struct TrPack { TrDesc t[12]; };

__global__ __launch_bounds__(256) void tr_all(TrPack p) {
  __shared__ float tile[32][33];
  const int bid = blockIdx.x;
  int i = 0;
#pragma unroll
  for (int j = 1; j < 12; ++j)
    if (bid >= p.t[j].t0) i = j;
  const float* src = p.t[i].s;
  u16* dst = p.t[i].d;
  const int R = p.t[i].R, C = p.t[i].C;
  const int lt = bid - p.t[i].t0;
  const int ntx = C >> 5;
  const int c0 = (lt % ntx) << 5, r0 = (lt / ntx) << 5;
  const int tx = threadIdx.x, ty = threadIdx.y;
#pragma unroll
  for (int j = 0; j < 4; ++j)
    tile[ty + 8 * j][tx] = src[(size_t)(r0 + ty + 8 * j) * C + c0 + tx];
  __syncthreads();
#pragma unroll
  for (int j = 0; j < 4; ++j)
    dst[(size_t)(c0 + ty + 8 * j) * R + r0 + tx] = f2bf(tile[tx][ty + 8 * j]);
}

// ---------------- u16 transpose (per-batch) -------------
__global__ __launch_bounds__(256) void tr16_k(const u16* __restrict__ src, u16* __restrict__ dst,
                                              int ss, int R) {
  __shared__ u16 tile[32][33];
  const int c0 = blockIdx.x * 32, r0 = blockIdx.y * 32;
  const int tx = threadIdx.x, ty = threadIdx.y;
#pragma unroll
  for (int j = 0; j < 4; ++j)
    tile[ty + 8 * j][tx] = src[(size_t)(r0 + ty + 8 * j) * ss + c0 + tx];
  __syncthreads();
  const int b = r0 / R, rb = r0 - b * R;
#pragma unroll
  for (int j = 0; j < 4; ++j)
    dst[(size_t)b * 1024 * R + (size_t)(c0 + ty + 8 * j) * R + rb + tx] = tile[tx][ty + 8 * j];
}

// ---------------- silu(c) -> bf16 -------------
__global__ __launch_bounds__(256) void silu_k(const float* __restrict__ c, u16* __restrict__ o, int n) {
  int i = blockIdx.x * 256 + threadIdx.x;
  if (i < n) { float x = c[i]; o[i] = f2bf(x / (1.0f + __expf(-x))); }
}

// ---------------- build concat [q2 | q] bf16 -------------
__global__ __launch_bounds__(256) void cat_k(const float* __restrict__ q2, const float* __restrict__ qr,
                                             u16* __restrict__ cat) {
  int i = blockIdx.x * 256 + threadIdx.x;
  int r = i >> 10, c = i & 1023;
  cat[(size_t)r * 2048 + c] = f2bf(q2[i]);
  cat[(size_t)r * 2048 + 1024 + c] = f2bf(qr[i]);
}

// ---------------- out = bf2f(s0)+bf2f(s1)+bias+res (MLP2 split-K reduce) -------------
__global__ __launch_bounds__(256) void red2_k(const u16* __restrict__ s0, const u16* __restrict__ s1,
                                              const float* __restrict__ bias, const float* __restrict__ res,
                                              float* __restrict__ out) {
  const int i = blockIdx.x * 256 + threadIdx.x;
  const uint2 a = ((const uint2*)s0)[i];
  const uint2 b = ((const uint2*)s1)[i];
  const float4 bv = ((const float4*)bias)[i & 255];
  const float4 rv = ((const float4*)res)[i];
  float4 v;
  v.x = bf2f((u16)(a.x & 0xffff)) + bf2f((u16)(b.x & 0xffff)) + bv.x + rv.x;
  v.y = bf2f((u16)(a.x >> 16))    + bf2f((u16)(b.x >> 16))    + bv.y + rv.y;
  v.z = bf2f((u16)(a.y & 0xffff)) + bf2f((u16)(b.y & 0xffff)) + bv.z + rv.z;
  v.w = bf2f((u16)(a.y >> 16))    + bf2f((u16)(b.y >> 16))    + bv.w + rv.w;
  ((float4*)out)[i] = v;
}

// ---------------- per-(b,t) softmax scale M -------------
__global__ __launch_bounds__(64) void mrow_k(const int* __restrict__ pm, float* __restrict__ M) {
  const int tid = threadIdx.x;
  const int b = tid >> 4, seg = tid & 15;
  int pre[32];
  int a = 1;
#pragma unroll
  for (int j = 0; j < 32; ++j) { a &= pm[b * 512 + seg * 32 + j]; pre[j] = a; }
  const int total = a;
  int excl = 1;
  for (int s = 0; s < 16; ++s) {
    int o = __shfl(total, (b << 4) + s, 64);
    if (s < seg) excl &= o;
  }
#pragma unroll
  for (int j = 0; j < 32; ++j)
    M[b * 512 + seg * 32 + j] = (excl & pre[j]) ? NEGV : 0.0f;
}

// ---------------- adaLN-modulated layernorm -------------
__global__ __launch_bounds__(256) void ln_mod_k(const float* __restrict__ X, const u16* __restrict__ MOD,
                                                u16* __restrict__ OUT, int chunk) {
  const int row = blockIdx.x;
  const int b = row >> 10, i = row & 1023, t = i >> 1;
  const int tid = threadIdx.x;
  const float4 xv = *(const float4*)&X[(size_t)row * 1024 + tid * 4];
  float s = xv.x + xv.y + xv.z + xv.w;
  float q = xv.x * xv.x + xv.y * xv.y + xv.z * xv.z + xv.w * xv.w;
#pragma unroll
  for (int off = 32; off > 0; off >>= 1) { s += __shfl_down(s, off); q += __shfl_down(q, off); }
  __shared__ float rs[4], rq[4];
  if ((tid & 63) == 0) { rs[tid >> 6] = s; rq[tid >> 6] = q; }
  __syncthreads();
  float S = rs[0] + rs[1] + rs[2] + rs[3];
  float Q = rq[0] + rq[1] + rq[2] + rq[3];
  const float mu = S * (1.0f / 1024.0f);
  const float var = Q * (1.0f / 1024.0f) - mu * mu;
  const float rstd = rsqrtf(var + 1e-6f);
  const u16* mrow = MOD + (size_t)(b * Tt + t) * 6144 + chunk * 1024 + tid * 4;
  u16* out = OUT + (size_t)row * 1024 + tid * 4;
  const float xx[4] = {xv.x, xv.y, xv.z, xv.w};
#pragma unroll
  for (int j = 0; j < 4; ++j) {
    float sc = bf2f(mrow[j]);
    float sh = bf2f(mrow[1024 + j]);
    out[j] = f2bf((xx[j] - mu) * rstd * (1.0f + sc) + sh);
  }
}

// ---------------- kin = ln(c+pe)*gk+bk ; vin = ln(c)*gv+bv -------------
__global__ __launch_bounds__(256) void ln_kv_k(const float* __restrict__ C_, const float* __restrict__ PE,
                                               const float* __restrict__ gk, const float* __restrict__ bk,
                                               const float* __restrict__ gv, const float* __restrict__ bv,
                                               u16* __restrict__ KIN, u16* __restrict__ VIN) {
  const int row = blockIdx.x, tid = threadIdx.x;
  const size_t base = (size_t)row * 1024 + tid * 4;
  const float4 cv = *(const float4*)&C_[base];
  const float4 pv = *(const float4*)&PE[base];
  const float a[4] = {cv.x + pv.x, cv.y + pv.y, cv.z + pv.z, cv.w + pv.w};
  const float bb[4] = {cv.x, cv.y, cv.z, cv.w};
  float sa = a[0] + a[1] + a[2] + a[3];
  float qa = a[0] * a[0] + a[1] * a[1] + a[2] * a[2] + a[3] * a[3];
  float sb = bb[0] + bb[1] + bb[2] + bb[3];
  float qb = bb[0] * bb[0] + bb[1] * bb[1] + bb[2] * bb[2] + bb[3] * bb[3];
#pragma unroll
  for (int off = 32; off > 0; off >>= 1) {
    sa += __shfl_down(sa, off); qa += __shfl_down(qa, off);
    sb += __shfl_down(sb, off); qb += __shfl_down(qb, off);
  }
  __shared__ float r4[4][4];
  if ((tid & 63) == 0) {
    int w = tid >> 6;
    r4[0][w] = sa; r4[1][w] = qa; r4[2][w] = sb; r4[3][w] = qb;
  }
  __syncthreads();
  sa = r4[0][0] + r4[0][1] + r4[0][2] + r4[0][3];
  qa = r4[1][0] + r4[1][1] + r4[1][2] + r4[1][3];
  sb = r4[2][0] + r4[2][1] + r4[2][2] + r4[2][3];
  qb = r4[3][0] + r4[3][1] + r4[3][2] + r4[3][3];
  const float mua = sa * (1.0f / 1024.0f);
  const float ra = rsqrtf(qa * (1.0f / 1024.0f) - mua * mua + 1e-5f);
  const float mub = sb * (1.0f / 1024.0f);
  const float rb = rsqrtf(qb * (1.0f / 1024.0f) - mub * mub + 1e-5f);
#pragma unroll
  for (int j = 0; j < 4; ++j) {
    int d = tid * 4 + j;
    KIN[(size_t)row * 1024 + d] = f2bf((a[j] - mua) * ra * gk[d] + bk[d]);
    VIN[(size_t)row * 1024 + d] = f2bf((bb[j] - mub) * rb * gv[d] + bv[d]);
  }
}

// ---------------- double-buffered GEMM core (128x128, BK=32) ----------------
DEV void stage32(const u16* __restrict__ A, const u16* __restrict__ Bt, int K,
                 int brow, int bcol, int kb, u16 (*As)[32], u16 (*Bs)[32]) {
  const int l = threadIdx.x & 63, wid = threadIdx.x >> 6;
#pragma unroll
  for (int p = 0; p < 2; ++p) {
    const int r0 = p * 64 + wid * 16;
    const int row = r0 + (l >> 2), kof = (l & 3) << 3;
    gload16(&A[(size_t)(brow + row) * K + kb + kof], &As[r0][0]);
    gload16(&Bt[(size_t)(bcol + row) * K + kb + kof], &Bs[r0][0]);
  }
}

DEV void gcore(const u16* __restrict__ A, const u16* __restrict__ Bt, int K,
               int brow, int bcol, int k0, int nk32,
               u16 (*As)[128][32], u16 (*Bs)[128][32], f32x4 (&acc)[4][4]) {
  const int l = threadIdx.x & 63, wid = threadIdx.x >> 6;
  const int wr = wid >> 1, wc = wid & 1;
  const int fr = l & 15, fg = l >> 4;
  stage32(A, Bt, K, brow, bcol, k0, As[0], Bs[0]);
  __syncthreads();
  int cur = 0;
  for (int kt = 0; kt < nk32; ++kt) {
    if (kt + 1 < nk32)
      stage32(A, Bt, K, brow, bcol, k0 + ((kt + 1) << 5), As[cur ^ 1], Bs[cur ^ 1]);
    bf16x8 af[4], bfr[4];
#pragma unroll
    for (int m = 0; m < 4; ++m) af[m] = *(const bf16x8*)&As[cur][wr * 64 + m * 16 + fr][fg * 8];
#pragma unroll
    for (int n = 0; n < 4; ++n) bfr[n] = *(const bf16x8*)&Bs[cur][wc * 64 + n * 16 + fr][fg * 8];
#pragma unroll
    for (int m = 0; m < 4; ++m)
#pragma unroll
      for (int n = 0; n < 4; ++n) acc[m][n] = mfma16(af[m], bfr[n], acc[m][n]);
    __syncthreads();
    cur ^= 1;
  }
}

// ---------------- generic 128x128 GEMM, bf16 out -------------
// EPI 0: bf16   1: bf16+bias   2: bf16+bias+gelu(sigmoid form)
template <int EPI>
__global__ __launch_bounds__(256) void gemm_k(const u16* __restrict__ A, const u16* __restrict__ Bt,
                                              int N, int K, const float* __restrict__ bias,
                                              u16* __restrict__ outb, int nbx) {
  __shared__ u16 As[2][128][32];
  __shared__ u16 Bs[2][128][32];
  const int wg = swz8(blockIdx.x, gridDim.x);
  const int brow = (wg / nbx) * 128, bcol = (wg % nbx) * 128;
  const int l = threadIdx.x & 63, wid = threadIdx.x >> 6;
  const int wr = wid >> 1, wc = wid & 1, fr = l & 15, fg = l >> 4;
  f32x4 acc[4][4];
#pragma unroll
  for (int m = 0; m < 4; ++m)
#pragma unroll
    for (int n = 0; n < 4; ++n) acc[m][n] = (f32x4){0.f, 0.f, 0.f, 0.f};
  gcore(A, Bt, K, brow, bcol, 0, K >> 5, As, Bs, acc);
#pragma unroll
  for (int m = 0; m < 4; ++m)
#pragma unroll
    for (int n = 0; n < 4; ++n)
#pragma unroll
      for (int r = 0; r < 4; ++r) {
        const int row = brow + wr * 64 + m * 16 + fg * 4 + r;
        const int col = bcol + wc * 64 + n * 16 + fr;
        float v = acc[m][n][r];
        if (EPI != 0) v += bias[col];
        if (EPI == 2) {
          const float u = v * (0.7978845608f + 0.0356774081f * v * v);
          v = v / (1.0f + __expf(-2.0f * u));
        }
        outb[(size_t)row * N + col] = f2bf(v);
      }
}

// ---------------- 128x64-tile GEMM, BK=32, direct f32 epilogue (NO atomics) -----------
// EPI 3: out = acc+bias+res   4: out = acc+bias   5: out(in-place) = (1+acc+bias)*q2 + out
template <int EPI>
__global__ __launch_bounds__(256) void gemm64(const u16* __restrict__ A, const u16* __restrict__ Bt,
                                              int N, int K, const float* __restrict__ bias,
                                              const float* __restrict__ res, const float* __restrict__ q2,
                                              float* __restrict__ outf, int nbx) {
  __shared__ u16 As[2][128][32];
  __shared__ u16 Bs[2][64][32];
  const int wg = swz8(blockIdx.x, gridDim.x);
  const int brow = (wg / nbx) * 128, bcol = (wg % nbx) * 64;
  const int l = threadIdx.x & 63, wid = threadIdx.x >> 6;
  const int wr = wid >> 1, wc = wid & 1, fr = l & 15, fg = l >> 4;
  const int srow = l >> 2, skof = (l & 3) << 3;

  f32x4 acc[4][2];
#pragma unroll
  for (int m = 0; m < 4; ++m)
#pragma unroll
    for (int n = 0; n < 2; ++n) acc[m][n] = (f32x4){0.f, 0.f, 0.f, 0.f};

  auto stg = [&](int kb, int cur) {
    gload16(&A[(size_t)(brow + wid * 32 + srow) * K + kb + skof], &As[cur][wid * 32][0]);
    gload16(&A[(size_t)(brow + wid * 32 + 16 + srow) * K + kb + skof], &As[cur][wid * 32 + 16][0]);
    gload16(&Bt[(size_t)(bcol + wid * 16 + srow) * K + kb + skof], &Bs[cur][wid * 16][0]);
  };

  stg(0, 0);
  __syncthreads();
  int cur = 0;
  const int nk32 = K >> 5;
  for (int kt = 0; kt < nk32; ++kt) {
    if (kt + 1 < nk32) stg((kt + 1) << 5, cur ^ 1);
    bf16x8 af[4], bfr[2];
#pragma unroll
    for (int m = 0; m < 4; ++m) af[m] = *(const bf16x8*)&As[cur][wr * 64 + m * 16 + fr][fg * 8];
#pragma unroll
    for (int n = 0; n < 2; ++n) bfr[n] = *(const bf16x8*)&Bs[cur][wc * 32 + n * 16 + fr][fg * 8];
#pragma unroll
    for (int m = 0; m < 4; ++m)
#pragma unroll
      for (int n = 0; n < 2; ++n) acc[m][n] = mfma16(af[m], bfr[n], acc[m][n]);
    __syncthreads();
    cur ^= 1;
  }

#pragma unroll
  for (int m = 0; m < 4; ++m)
#pragma unroll
    for (int n = 0; n < 2; ++n)
#pragma unroll
      for (int r = 0; r < 4; ++r) {
        const int row = brow + wr * 64 + m * 16 + fg * 4 + r;
        const int col = bcol + wc * 32 + n * 16 + fr;
        const size_t o = (size_t)row * N + col;
        const float v = acc[m][n][r] + bias[col];
        if (EPI == 3) outf[o] = v + res[o];
        else if (EPI == 4) outf[o] = v;
        else outf[o] = (1.0f + v) * q2[o] + outf[o];
      }
}

// ---------------- 256x64-tile split-K=2 GEMM, BK=32, bf16 partial sums -------------
// Each wave owns a 64x64 sub-tile -> acc[4][4], 16 MFMAs/K-step (128^2-level barrier
// amortization) while keeping grid 256x2 = 512 blocks. LDS 40KB -> 4 blocks/CU.
__global__ __launch_bounds__(256) void gemm64b(const u16* __restrict__ A, const u16* __restrict__ Bt,
                                               int N, int K, u16* __restrict__ sk0, u16* __restrict__ sk1,
                                               int nbx) {
  __shared__ u16 As[2][256][32];
  __shared__ u16 Bs[2][64][32];
  const int wg = swz8(blockIdx.x, gridDim.x);
  const int brow = (wg / nbx) * 256, bcol = (wg % nbx) * 64;
  const int kper = K >> 1;
  const int k0 = blockIdx.y * kper;
  const int l = threadIdx.x & 63, wid = threadIdx.x >> 6;
  const int fr = l & 15, fg = l >> 4;
  const int srow = l >> 2, skof = (l & 3) << 3;   // 16-row chunk staging

  f32x4 acc[4][4];
#pragma unroll
  for (int m = 0; m < 4; ++m)
#pragma unroll
    for (int n = 0; n < 4; ++n) acc[m][n] = (f32x4){0.f, 0.f, 0.f, 0.f};

  auto stg = [&](int kb, int cur) {   // 5 ops/wave: A rows [wid*64,+64), B rows [wid*16,+16)
#pragma unroll
    for (int p = 0; p < 4; ++p)
      gload16(&A[(size_t)(brow + wid * 64 + p * 16 + srow) * K + kb + skof], &As[cur][wid * 64 + p * 16][0]);
    gload16(&Bt[(size_t)(bcol + wid * 16 + srow) * K + kb + skof], &Bs[cur][wid * 16][0]);
  };

  stg(k0, 0);
  __syncthreads();
  int cur = 0;
  const int nk32 = kper >> 5;
  for (int kt = 0; kt < nk32; ++kt) {
    if (kt + 1 < nk32) stg(k0 + ((kt + 1) << 5), cur ^ 1);
    bf16x8 af[4], bfr[4];
#pragma unroll
    for (int m = 0; m < 4; ++m) af[m] = *(const bf16x8*)&As[cur][wid * 64 + m * 16 + fr][fg * 8];
#pragma unroll
    for (int n = 0; n < 4; ++n) bfr[n] = *(const bf16x8*)&Bs[cur][n * 16 + fr][fg * 8];
#pragma unroll
    for (int m = 0; m < 4; ++m)
#pragma unroll
      for (int n = 0; n < 4; ++n) acc[m][n] = mfma16(af[m], bfr[n], acc[m][n]);
    __syncthreads();
    cur ^= 1;
  }

  u16* out = blockIdx.y ? sk1 : sk0;
#pragma unroll
  for (int m = 0; m < 4; ++m)
#pragma unroll
    for (int n = 0; n < 4; ++n)
#pragma unroll
      for (int r = 0; r < 4; ++r) {
        const int row = brow + wid * 64 + m * 16 + fg * 4 + r;
        const int col = bcol + n * 16 + fr;
        out[(size_t)row * N + col] = f2bf(acc[m][n][r]);
      }
}

// ---------------- CA grouped GEMM -------------
__global__ __launch_bounds__(256) void gemm3_k(const u16* A0, const u16* A1, const u16* A2,
                                               const u16* B0, const u16* B1, const u16* B2,
                                               u16* O0, u16* O1, u16* O2) {
  const int z = blockIdx.y;
  const int wg = swz8(blockIdx.x, gridDim.x);
  const int bx = wg & 7, by = wg >> 3;
  if (z > 0 && by >= 16) return;
  const u16* A = z == 0 ? A0 : (z == 1 ? A1 : A2);
  const u16* Bt = z == 0 ? B0 : (z == 1 ? B1 : B2);
  u16* O = z == 0 ? O0 : (z == 1 ? O1 : O2);
  __shared__ u16 As[2][128][32];
  __shared__ u16 Bs[2][128][32];
  const int brow = by * 128, bcol = bx * 128;
  const int l = threadIdx.x & 63, wid = threadIdx.x >> 6;
  const int wr = wid >> 1, wc = wid & 1, fr = l & 15, fg = l >> 4;
  f32x4 acc[4][4];
#pragma unroll
  for (int m = 0; m < 4; ++m)
#pragma unroll
    for (int n = 0; n < 4; ++n) acc[m][n] = (f32x4){0.f, 0.f, 0.f, 0.f};
  gcore(A, Bt, 1024, brow, bcol, 0, 32, As, Bs, acc);
#pragma unroll
  for (int m = 0; m < 4; ++m)
#pragma unroll
    for (int n = 0; n < 4; ++n)
#pragma unroll
      for (int r = 0; r < 4; ++r) {
        const int row = brow + wr * 64 + m * 16 + fg * 4 + r;
        const int col = bcol + wc * 64 + n * 16 + fr;
        O[(size_t)row * 1024 + col] = f2bf(acc[m][n][r]);
      }
}

// ---------------- flash attention: shared dbuf K/V staging (R14) -------------
template <int QDIV, int PDIV>
__global__ __launch_bounds__(256) void attn_k(const u16* __restrict__ QH, const u16* __restrict__ KH,
                                              const u16* __restrict__ VT, u16* __restrict__ AO,
                                              const int* __restrict__ pmask, const float* __restrict__ Mrow,
                                              int Nq, int Nk, int qs, int ks) {
  __shared__ u16 KS[2][2048];
  __shared__ u16 VS[2][2048];
  __shared__ u16 PL[4][16][40];
  const int tid = threadIdx.x;
  const int l = tid & 63, wid = tid >> 6;
  const int fr = l & 15, fg = l >> 4;
  const int nqb = Nq >> 6;
  const int wgid = swz8(blockIdx.x, gridDim.x);
  const int qb = wgid % nqb;
  const int bh = wgid / nqb;
  const int h = bh & 15, b = bh >> 4;
  const int q0 = qb * 64 + wid * 16;

  u16 (*Pl)[40] = PL[wid];

  const int krow = l >> 3;
  const int kslot = (l & 7) ^ krow;
  const int vrow = l >> 2;
  const int vslot = (l & 3) ^ (vrow & 3);

  const size_t qrow = (size_t)(b * Nq + q0 + fr) * qs + h * 64;
  const bf16x8 aq0 = *(const bf16x8*)&QH[qrow + fg * 8];
  const bf16x8 aq1 = *(const bf16x8*)&QH[qrow + 32 + fg * 8];

  float Mr[4];
#pragma unroll
  for (int r = 0; r < 4; ++r) Mr[r] = Mrow[b * Tt + ((q0 + fg * 4 + r) >> 1)];

  f32x4 o[4];
#pragma unroll
  for (int c = 0; c < 4; ++c) o[c] = (f32x4){0.f, 0.f, 0.f, 0.f};
  float lsum[4] = {0.f, 0.f, 0.f, 0.f};

  int nkt = Nk >> 5;
  if (Mrow[b * Tt + ((qb * 64) >> 1)] == 0.0f) {
    const int kallow = (qb * 64 + 63) / QDIV + 1;
    const int t = (kallow + 31) >> 5;
    if (t < nkt) nkt = t;
  }

  const int sw0 = (fg ^ (fr & 7)) * 8;
  const int sw1 = ((4 + fg) ^ (fr & 7)) * 8;
  const size_t vtb = (size_t)b * 1024 * Nk + (size_t)(h * 64) * Nk;

  auto stage = [&](int kb, int buf) {
    gload16(&KH[(size_t)(b * Nk + kb + wid * 8 + krow) * ks + h * 64 + kslot * 8], &KS[buf][wid * 512]);
    gload16(&VT[vtb + (size_t)(wid * 16 + vrow) * Nk + kb + vslot * 8], &VS[buf][wid * 512]);
  };

  stage(0, 0);
  __syncthreads();
  int buf = 0;

  for (int kt = 0; kt < nkt; ++kt) {
    const int kb = kt << 5;
    if (kt + 1 < nkt) stage((kt + 1) << 5, buf ^ 1);

    const u16* Ksl = KS[buf];
    const u16* Vsl = VS[buf];

    f32x4 s0 = (f32x4){0.f, 0.f, 0.f, 0.f}, s1 = (f32x4){0.f, 0.f, 0.f, 0.f};
    {
      bf16x8 kf;
      kf = *(const bf16x8*)&Ksl[fr * 64 + sw0];        s0 = mfma16(aq0, kf, s0);
      kf = *(const bf16x8*)&Ksl[fr * 64 + sw1];        s0 = mfma16(aq1, kf, s0);
      kf = *(const bf16x8*)&Ksl[(16 + fr) * 64 + sw0]; s1 = mfma16(aq0, kf, s1);
      kf = *(const bf16x8*)&Ksl[(16 + fr) * 64 + sw1]; s1 = mfma16(aq1, kf, s1);
    }
    const int c0 = kb + fr, c1 = kb + 16 + fr;
    const float pad0 = pmask[b * Tt + (PDIV == 2 ? (c0 >> 1) : c0)] ? NEGV : 0.0f;
    const float pad1 = pmask[b * Tt + (PDIV == 2 ? (c1 >> 1) : c1)] ? NEGV : 0.0f;

#pragma unroll
    for (int r = 0; r < 4; ++r) {
      const int rq = (q0 + fg * 4 + r) >> (QDIV == 2 ? 1 : 0);
      float v0 = s0[r] * 0.125f; v0 = (c0 <= rq) ? v0 : NEGV; v0 += pad0;
      float v1 = s1[r] * 0.125f; v1 = (c1 <= rq) ? v1 : NEGV; v1 += pad1;
      const float p0 = __expf(v0 - Mr[r]);
      const float p1 = __expf(v1 - Mr[r]);
      lsum[r] += p0 + p1;
      Pl[fg * 4 + r][fr] = f2bf(p0);
      Pl[fg * 4 + r][16 + fr] = f2bf(p1);
    }

    const bf16x8 pa = *(const bf16x8*)&Pl[fr][fg * 8];
#pragma unroll
    for (int c = 0; c < 4; ++c) {
      const bf16x8 vb = *(const bf16x8*)&Vsl[(c * 16 + fr) * 32 + ((fg ^ (fr & 3)) << 3)];
      o[c] = mfma16(pa, vb, o[c]);
    }
    __syncthreads();
    buf ^= 1;
  }

#pragma unroll
  for (int r = 0; r < 4; ++r) {
    lsum[r] += __shfl_xor(lsum[r], 1);
    lsum[r] += __shfl_xor(lsum[r], 2);
    lsum[r] += __shfl_xor(lsum[r], 4);
    lsum[r] += __shfl_xor(lsum[r], 8);
  }

#pragma unroll
  for (int c = 0; c < 4; ++c)
#pragma unroll
    for (int r = 0; r < 4; ++r) {
      const int row = q0 + fg * 4 + r;
      AO[(size_t)(b * Nq + row) * Dd + h * 64 + c * 16 + fr] = f2bf(o[c][r] / lsum[r]);
    }
}

// =======================================================================================
extern "C" void kernel_launch(void* const* d_in, const int* in_sizes, int n_in,
                              void* d_out, int out_size, void* d_ws, size_t ws_size,
                              hipStream_t stream) {
  (void)in_sizes; (void)n_in; (void)out_size; (void)ws_size;
  const float* q_in   = (const float*)d_in[0];
  const float* c_in   = (const float*)d_in[1];
  const float* pe     = (const float*)d_in[2];
  const int*   pmask  = (const int*)d_in[3];
  const float* w_mod  = (const float*)d_in[4];
  const float* b_mod  = (const float*)d_in[5];
  const float* sa_wq  = (const float*)d_in[6];
  const float* sa_wk  = (const float*)d_in[7];
  const float* sa_wv  = (const float*)d_in[8];
  const float* sa_wo  = (const float*)d_in[9];
  const float* sa_bo  = (const float*)d_in[10];
  const float* ca_wq  = (const float*)d_in[11];
  const float* ca_wk  = (const float*)d_in[12];
  const float* ca_wv  = (const float*)d_in[13];
  const float* ca_wo  = (const float*)d_in[14];
  const float* ca_bo  = (const float*)d_in[15];
  const float* gk     = (const float*)d_in[16];
  const float* bk     = (const float*)d_in[17];
  const float* gv     = (const float*)d_in[18];
  const float* bv     = (const float*)d_in[19];
  const float* w_alpha= (const float*)d_in[20];
  const float* b_alpha= (const float*)d_in[21];
  const float* w1     = (const float*)d_in[22];
  const float* b1     = (const float*)d_in[23];
  const float* w2     = (const float*)d_in[24];
  const float* b2     = (const float*)d_in[25];

  // ---- workspace layout (u16 element offsets) ----
  u16* ws = (u16*)d_ws;
  u16* WMODt  = ws + 0;                     // [6144][1024]; dead after mod GEMM
  float* Mp   = (float*)(ws + 4194304);     // [4][512] overlay in dead WMODt tail
  u16* SK1b   = WMODt;                      // MLP2 split-1 (dead WMODt head)
  u16* SAWQt  = ws + 6291456;
  u16* SAWKt  = ws + 7340032;
  u16* SAWVt  = ws + 8388608;
  u16* SAWOt  = ws + 9437184;
  u16* CAWQt  = ws + 10485760;
  u16* CAWKt  = ws + 11534336;
  u16* CAWVt  = ws + 12582912;
  u16* CAWOt  = ws + 13631488;
  u16* WALPHt = ws + 14680064;
  u16* W1t    = ws + 16777216;
  u16* W2t    = ws + 20971520;
  u16* Xs     = ws + 25165824;              // silu(c); dead after mod GEMM
  u16* KINp   = Xs;
  u16* VINp   = SAWQt;
  u16* MODbf  = ws + 27262976;              // [2048][6144]
  u16* LNO    = ws + 39845888;
  u16* SK0b   = LNO;                        // MLP2 split-0 (LNO dead after MLP1)
  u16* BIG    = ws + 44040192;
  u16* QKVp = BIG;
  u16* VTsa = BIG + 12582912;
  u16* AOp  = LNO;
  u16* CAQp = BIG;
  u16* CAKp = BIG + 4194304;
  u16* CAVp = BIG + 6291456;
  u16* VT2  = BIG + 8388608;
  u16* AO2p = BIG + 10485760;
  u16* CATp = BIG;
  u16* HBp  = BIG;
  float* Qres = (float*)(ws + 60817408);
  float* Q2f  = Qres + 4194304;
  float* outp = (float*)d_out;

  const dim3 blk(256);

  // ---- all 12 weight transposes in ONE launch ----
  TrPack pk;
  int off = 0;
  auto add = [&](int i, const float* s, u16* d, int R, int C) {
    pk.t[i].s = s; pk.t[i].d = d; pk.t[i].R = R; pk.t[i].C = C; pk.t[i].t0 = off;
    off += (C >> 5) * (R >> 5);
  };
  add(0, w_mod, WMODt, 1024, 6144);
  add(1, sa_wq, SAWQt, 1024, 1024);
  add(2, sa_wk, SAWKt, 1024, 1024);
  add(3, sa_wv, SAWVt, 1024, 1024);
  add(4, sa_wo, SAWOt, 1024, 1024);
  add(5, ca_wq, CAWQt, 1024, 1024);
  add(6, ca_wk, CAWKt, 1024, 1024);
  add(7, ca_wv, CAWVt, 1024, 1024);
  add(8, ca_wo, CAWOt, 1024, 1024);
  add(9, w_alpha, WALPHt, 2048, 1024);
  add(10, w1, W1t, 1024, 4096);
  add(11, w2, W2t, 4096, 1024);
  tr_all<<<off, dim3(32, 8), 0, stream>>>(pk);

  // modulation
  silu_k<<<8192, blk, 0, stream>>>(c_in, Xs, 2048 * 1024);
  gemm_k<1><<<768, blk, 0, stream>>>(Xs, WMODt, 6144, 1024, b_mod, MODbf, 48);
  mrow_k<<<1, 64, 0, stream>>>(pmask, Mp);

  // ---- self-attention ----
  ln_mod_k<<<4096, blk, 0, stream>>>(q_in, MODbf, LNO, 0);
  gemm_k<0><<<768, blk, 0, stream>>>(LNO, SAWQt, 3072, 1024, nullptr, QKVp, 24);
  tr16_k<<<dim3(32, 128), dim3(32, 8), 0, stream>>>(QKVp + 2048, VTsa, 3072, 1024);
  ln_kv_k<<<2048, blk, 0, stream>>>(c_in, pe, gk, bk, gv, bv, KINp, VINp);
  attn_k<1, 2><<<1024, blk, 0, stream>>>(QKVp, QKVp + 1024, VTsa, AOp, pmask, Mp,
                                         1024, 1024, 3072, 3072);
  gemm64<3><<<512, blk, 0, stream>>>(AOp, SAWOt, 1024, 1024, sa_bo, q_in, nullptr, Qres, 16);

  // ---- cross-attention ----
  ln_mod_k<<<4096, blk, 0, stream>>>(Qres, MODbf, LNO, 2);
  gemm3_k<<<dim3(256, 3), blk, 0, stream>>>(LNO, KINp, VINp, CAWQt, CAWKt, CAWVt, CAQp, CAKp, CAVp);
  tr16_k<<<dim3(32, 64), dim3(32, 8), 0, stream>>>(CAVp, VT2, 1024, 512);
  attn_k<2, 1><<<1024, blk, 0, stream>>>(CAQp, CAKp, VT2, AO2p, pmask, Mp,
                                         1024, 512, 1024, 1024);
  gemm64<4><<<512, blk, 0, stream>>>(AO2p, CAWOt, 1024, 1024, ca_bo, nullptr, nullptr, Q2f, 16);
  cat_k<<<16384, blk, 0, stream>>>(Q2f, Qres, CATp);
  gemm64<5><<<512, blk, 0, stream>>>(CATp, WALPHt, 1024, 2048, b_alpha, nullptr, Q2f, Qres, 16);

  // ---- MLP ----
  ln_mod_k<<<4096, blk, 0, stream>>>(Qres, MODbf, LNO, 4);
  gemm_k<2><<<1024, blk, 0, stream>>>(LNO, W1t, 4096, 1024, b1, HBp, 32);
  gemm64b<<<dim3(256, 2), blk, 0, stream>>>(HBp, W2t, 1024, 4096, SK0b, SK1b, 16);
  red2_k<<<4096, blk, 0, stream>>>(SK0b, SK1b, b2, Qres, outp);
}

// Round 20
// 460.387 us; speedup vs baseline: 1.0146x; 1.0146x over previous
//
#include <hip/hip_runtime.h>
#include <cstdint>

typedef unsigned short u16;
typedef __attribute__((ext_vector_type(8))) short bf16x8;
typedef __attribute__((ext_vector_type(4))) float f32x4;

#define DEV static __device__ __forceinline__
#define AS1 __attribute__((address_space(1)))
#define AS3 __attribute__((address_space(3)))

static constexpr int Bb = 4, Tt = 512, Nn = 1024, Dd = 1024, Hh = 16;
static constexpr float NEGV = -10000.0f;

DEV u16 f2bf(float f) {
  unsigned int u = __builtin_bit_cast(unsigned int, f);
  u += 0x7fffu + ((u >> 16) & 1u);
  return (u16)(u >> 16);
}
DEV float bf2f(u16 s) {
  unsigned int u = ((unsigned int)s) << 16;
  return __builtin_bit_cast(float, u);
}
DEV f32x4 mfma16(bf16x8 a, bf16x8 b, f32x4 c) {
  return __builtin_amdgcn_mfma_f32_16x16x32_bf16(a, b, c, 0, 0, 0);
}
DEV void gload16(const u16* g, u16* lds) {
  __builtin_amdgcn_global_load_lds((AS1 const unsigned int*)g, (AS3 unsigned int*)lds, 16, 0, 0);
}
// chunked XCD swizzle; requires nwg % 8 == 0
DEV int swz8(int wg, int nwg) { const int c = nwg >> 3; return (wg & 7) * c + (wg >> 3); }

// ---------------- batched transpose+cast: 12 weights in ONE launch ----------------
struct TrDesc { const float* s; u16* d; int R, C, t0; };
struct TrPack { TrDesc t[12]; };

__global__ __launch_bounds__(256) void tr_all(TrPack p) {
  __shared__ float tile[32][33];
  const int bid = blockIdx.x;
  int i = 0;
#pragma unroll
  for (int j = 1; j < 12; ++j)
    if (bid >= p.t[j].t0) i = j;
  const float* src = p.t[i].s;
  u16* dst = p.t[i].d;
  const int R = p.t[i].R, C = p.t[i].C;
  const int lt = bid - p.t[i].t0;
  const int ntx = C >> 5;
  const int c0 = (lt % ntx) << 5, r0 = (lt / ntx) << 5;
  const int tx = threadIdx.x, ty = threadIdx.y;
#pragma unroll
  for (int j = 0; j < 4; ++j)
    tile[ty + 8 * j][tx] = src[(size_t)(r0 + ty + 8 * j) * C + c0 + tx];
  __syncthreads();
#pragma unroll
  for (int j = 0; j < 4; ++j)
    dst[(size_t)(c0 + ty + 8 * j) * R + r0 + tx] = f2bf(tile[tx][ty + 8 * j]);
}

// ---------------- u16 transpose (per-batch) -------------
__global__ __launch_bounds__(256) void tr16_k(const u16* __restrict__ src, u16* __restrict__ dst,
                                              int ss, int R) {
  __shared__ u16 tile[32][33];
  const int c0 = blockIdx.x * 32, r0 = blockIdx.y * 32;
  const int tx = threadIdx.x, ty = threadIdx.y;
#pragma unroll
  for (int j = 0; j < 4; ++j)
    tile[ty + 8 * j][tx] = src[(size_t)(r0 + ty + 8 * j) * ss + c0 + tx];
  __syncthreads();
  const int b = r0 / R, rb = r0 - b * R;
#pragma unroll
  for (int j = 0; j < 4; ++j)
    dst[(size_t)b * 1024 * R + (size_t)(c0 + ty + 8 * j) * R + rb + tx] = tile[tx][ty + 8 * j];
}

// ---------------- silu(c) -> bf16 -------------
__global__ __launch_bounds__(256) void silu_k(const float* __restrict__ c, u16* __restrict__ o, int n) {
  int i = blockIdx.x * 256 + threadIdx.x;
  if (i < n) { float x = c[i]; o[i] = f2bf(x / (1.0f + __expf(-x))); }
}

// ---------------- build concat [q2 | q] bf16 -------------
__global__ __launch_bounds__(256) void cat_k(const float* __restrict__ q2, const float* __restrict__ qr,
                                             u16* __restrict__ cat) {
  int i = blockIdx.x * 256 + threadIdx.x;
  int r = i >> 10, c = i & 1023;
  cat[(size_t)r * 2048 + c] = f2bf(q2[i]);
  cat[(size_t)r * 2048 + 1024 + c] = f2bf(qr[i]);
}

// ---------------- out = bf2f(s0)+bf2f(s1)+bias+res (MLP2 split-K reduce) -------------
__global__ __launch_bounds__(256) void red2_k(const u16* __restrict__ s0, const u16* __restrict__ s1,
                                              const float* __restrict__ bias, const float* __restrict__ res,
                                              float* __restrict__ out) {
  const int i = blockIdx.x * 256 + threadIdx.x;
  const uint2 a = ((const uint2*)s0)[i];
  const uint2 b = ((const uint2*)s1)[i];
  const float4 bv = ((const float4*)bias)[i & 255];
  const float4 rv = ((const float4*)res)[i];
  float4 v;
  v.x = bf2f((u16)(a.x & 0xffff)) + bf2f((u16)(b.x & 0xffff)) + bv.x + rv.x;
  v.y = bf2f((u16)(a.x >> 16))    + bf2f((u16)(b.x >> 16))    + bv.y + rv.y;
  v.z = bf2f((u16)(a.y & 0xffff)) + bf2f((u16)(b.y & 0xffff)) + bv.z + rv.z;
  v.w = bf2f((u16)(a.y >> 16))    + bf2f((u16)(b.y >> 16))    + bv.w + rv.w;
  ((float4*)out)[i] = v;
}

// ---------------- per-(b,t) softmax scale M -------------
__global__ __launch_bounds__(64) void mrow_k(const int* __restrict__ pm, float* __restrict__ M) {
  const int tid = threadIdx.x;
  const int b = tid >> 4, seg = tid & 15;
  int pre[32];
  int a = 1;
#pragma unroll
  for (int j = 0; j < 32; ++j) { a &= pm[b * 512 + seg * 32 + j]; pre[j] = a; }
  const int total = a;
  int excl = 1;
  for (int s = 0; s < 16; ++s) {
    int o = __shfl(total, (b << 4) + s, 64);
    if (s < seg) excl &= o;
  }
#pragma unroll
  for (int j = 0; j < 32; ++j)
    M[b * 512 + seg * 32 + j] = (excl & pre[j]) ? NEGV : 0.0f;
}

// ---------------- adaLN-modulated layernorm -------------
__global__ __launch_bounds__(256) void ln_mod_k(const float* __restrict__ X, const u16* __restrict__ MOD,
                                                u16* __restrict__ OUT, int chunk) {
  const int row = blockIdx.x;
  const int b = row >> 10, i = row & 1023, t = i >> 1;
  const int tid = threadIdx.x;
  const float4 xv = *(const float4*)&X[(size_t)row * 1024 + tid * 4];
  float s = xv.x + xv.y + xv.z + xv.w;
  float q = xv.x * xv.x + xv.y * xv.y + xv.z * xv.z + xv.w * xv.w;
#pragma unroll
  for (int off = 32; off > 0; off >>= 1) { s += __shfl_down(s, off); q += __shfl_down(q, off); }
  __shared__ float rs[4], rq[4];
  if ((tid & 63) == 0) { rs[tid >> 6] = s; rq[tid >> 6] = q; }
  __syncthreads();
  float S = rs[0] + rs[1] + rs[2] + rs[3];
  float Q = rq[0] + rq[1] + rq[2] + rq[3];
  const float mu = S * (1.0f / 1024.0f);
  const float var = Q * (1.0f / 1024.0f) - mu * mu;
  const float rstd = rsqrtf(var + 1e-6f);
  const u16* mrow = MOD + (size_t)(b * Tt + t) * 6144 + chunk * 1024 + tid * 4;
  u16* out = OUT + (size_t)row * 1024 + tid * 4;
  const float xx[4] = {xv.x, xv.y, xv.z, xv.w};
#pragma unroll
  for (int j = 0; j < 4; ++j) {
    float sc = bf2f(mrow[j]);
    float sh = bf2f(mrow[1024 + j]);
    out[j] = f2bf((xx[j] - mu) * rstd * (1.0f + sc) + sh);
  }
}

// ---------------- kin = ln(c+pe)*gk+bk ; vin = ln(c)*gv+bv -------------
__global__ __launch_bounds__(256) void ln_kv_k(const float* __restrict__ C_, const float* __restrict__ PE,
                                               const float* __restrict__ gk, const float* __restrict__ bk,
                                               const float* __restrict__ gv, const float* __restrict__ bv,
                                               u16* __restrict__ KIN, u16* __restrict__ VIN) {
  const int row = blockIdx.x, tid = threadIdx.x;
  const size_t base = (size_t)row * 1024 + tid * 4;
  const float4 cv = *(const float4*)&C_[base];
  const float4 pv = *(const float4*)&PE[base];
  const float a[4] = {cv.x + pv.x, cv.y + pv.y, cv.z + pv.z, cv.w + pv.w};
  const float bb[4] = {cv.x, cv.y, cv.z, cv.w};
  float sa = a[0] + a[1] + a[2] + a[3];
  float qa = a[0] * a[0] + a[1] * a[1] + a[2] * a[2] + a[3] * a[3];
  float sb = bb[0] + bb[1] + bb[2] + bb[3];
  float qb = bb[0] * bb[0] + bb[1] * bb[1] + bb[2] * bb[2] + bb[3] * bb[3];
#pragma unroll
  for (int off = 32; off > 0; off >>= 1) {
    sa += __shfl_down(sa, off); qa += __shfl_down(qa, off);
    sb += __shfl_down(sb, off); qb += __shfl_down(qb, off);
  }
  __shared__ float r4[4][4];
  if ((tid & 63) == 0) {
    int w = tid >> 6;
    r4[0][w] = sa; r4[1][w] = qa; r4[2][w] = sb; r4[3][w] = qb;
  }
  __syncthreads();
  sa = r4[0][0] + r4[0][1] + r4[0][2] + r4[0][3];
  qa = r4[1][0] + r4[1][1] + r4[1][2] + r4[1][3];
  sb = r4[2][0] + r4[2][1] + r4[2][2] + r4[2][3];
  qb = r4[3][0] + r4[3][1] + r4[3][2] + r4[3][3];
  const float mua = sa * (1.0f / 1024.0f);
  const float ra = rsqrtf(qa * (1.0f / 1024.0f) - mua * mua + 1e-5f);
  const float mub = sb * (1.0f / 1024.0f);
  const float rb = rsqrtf(qb * (1.0f / 1024.0f) - mub * mub + 1e-5f);
#pragma unroll
  for (int j = 0; j < 4; ++j) {
    int d = tid * 4 + j;
    KIN[(size_t)row * 1024 + d] = f2bf((a[j] - mua) * ra * gk[d] + bk[d]);
    VIN[(size_t)row * 1024 + d] = f2bf((bb[j] - mub) * rb * gv[d] + bv[d]);
  }
}

// ---------------- double-buffered GEMM core (128x128, BK=32) ----------------
DEV void stage32(const u16* __restrict__ A, const u16* __restrict__ Bt, int K,
                 int brow, int bcol, int kb, u16 (*As)[32], u16 (*Bs)[32]) {
  const int l = threadIdx.x & 63, wid = threadIdx.x >> 6;
#pragma unroll
  for (int p = 0; p < 2; ++p) {
    const int r0 = p * 64 + wid * 16;
    const int row = r0 + (l >> 2), kof = (l & 3) << 3;
    gload16(&A[(size_t)(brow + row) * K + kb + kof], &As[r0][0]);
    gload16(&Bt[(size_t)(bcol + row) * K + kb + kof], &Bs[r0][0]);
  }
}

DEV void gcore(const u16* __restrict__ A, const u16* __restrict__ Bt, int K,
               int brow, int bcol, int k0, int nk32,
               u16 (*As)[128][32], u16 (*Bs)[128][32], f32x4 (&acc)[4][4]) {
  const int l = threadIdx.x & 63, wid = threadIdx.x >> 6;
  const int wr = wid >> 1, wc = wid & 1;
  const int fr = l & 15, fg = l >> 4;
  stage32(A, Bt, K, brow, bcol, k0, As[0], Bs[0]);
  __syncthreads();
  int cur = 0;
  for (int kt = 0; kt < nk32; ++kt) {
    if (kt + 1 < nk32)
      stage32(A, Bt, K, brow, bcol, k0 + ((kt + 1) << 5), As[cur ^ 1], Bs[cur ^ 1]);
    bf16x8 af[4], bfr[4];
#pragma unroll
    for (int m = 0; m < 4; ++m) af[m] = *(const bf16x8*)&As[cur][wr * 64 + m * 16 + fr][fg * 8];
#pragma unroll
    for (int n = 0; n < 4; ++n) bfr[n] = *(const bf16x8*)&Bs[cur][wc * 64 + n * 16 + fr][fg * 8];
#pragma unroll
    for (int m = 0; m < 4; ++m)
#pragma unroll
      for (int n = 0; n < 4; ++n) acc[m][n] = mfma16(af[m], bfr[n], acc[m][n]);
    __syncthreads();
    cur ^= 1;
  }
}

// ---------------- generic 128x128 GEMM, bf16 out -------------
// EPI 0: bf16   1: bf16+bias   2: bf16+bias+gelu(sigmoid form)
template <int EPI>
__global__ __launch_bounds__(256) void gemm_k(const u16* __restrict__ A, const u16* __restrict__ Bt,
                                              int N, int K, const float* __restrict__ bias,
                                              u16* __restrict__ outb, int nbx) {
  __shared__ u16 As[2][128][32];
  __shared__ u16 Bs[2][128][32];
  const int wg = swz8(blockIdx.x, gridDim.x);
  const int brow = (wg / nbx) * 128, bcol = (wg % nbx) * 128;
  const int l = threadIdx.x & 63, wid = threadIdx.x >> 6;
  const int wr = wid >> 1, wc = wid & 1, fr = l & 15, fg = l >> 4;
  f32x4 acc[4][4];
#pragma unroll
  for (int m = 0; m < 4; ++m)
#pragma unroll
    for (int n = 0; n < 4; ++n) acc[m][n] = (f32x4){0.f, 0.f, 0.f, 0.f};
  gcore(A, Bt, K, brow, bcol, 0, K >> 5, As, Bs, acc);
#pragma unroll
  for (int m = 0; m < 4; ++m)
#pragma unroll
    for (int n = 0; n < 4; ++n)
#pragma unroll
      for (int r = 0; r < 4; ++r) {
        const int row = brow + wr * 64 + m * 16 + fg * 4 + r;
        const int col = bcol + wc * 64 + n * 16 + fr;
        float v = acc[m][n][r];
        if (EPI != 0) v += bias[col];
        if (EPI == 2) {
          const float u = v * (0.7978845608f + 0.0356774081f * v * v);
          v = v / (1.0f + __expf(-2.0f * u));
        }
        outb[(size_t)row * N + col] = f2bf(v);
      }
}

// ---------------- 128x64-tile GEMM, BK=32, direct f32 epilogue (NO atomics) -----------
// EPI 3: out = acc+bias+res   4: out = acc+bias   5: out(in-place) = (1+acc+bias)*q2 + out
template <int EPI>
__global__ __launch_bounds__(256) void gemm64(const u16* __restrict__ A, const u16* __restrict__ Bt,
                                              int N, int K, const float* __restrict__ bias,
                                              const float* __restrict__ res, const float* __restrict__ q2,
                                              float* __restrict__ outf, int nbx) {
  __shared__ u16 As[2][128][32];
  __shared__ u16 Bs[2][64][32];
  const int wg = swz8(blockIdx.x, gridDim.x);
  const int brow = (wg / nbx) * 128, bcol = (wg % nbx) * 64;
  const int l = threadIdx.x & 63, wid = threadIdx.x >> 6;
  const int wr = wid >> 1, wc = wid & 1, fr = l & 15, fg = l >> 4;
  const int srow = l >> 2, skof = (l & 3) << 3;

  f32x4 acc[4][2];
#pragma unroll
  for (int m = 0; m < 4; ++m)
#pragma unroll
    for (int n = 0; n < 2; ++n) acc[m][n] = (f32x4){0.f, 0.f, 0.f, 0.f};

  auto stg = [&](int kb, int cur) {
    gload16(&A[(size_t)(brow + wid * 32 + srow) * K + kb + skof], &As[cur][wid * 32][0]);
    gload16(&A[(size_t)(brow + wid * 32 + 16 + srow) * K + kb + skof], &As[cur][wid * 32 + 16][0]);
    gload16(&Bt[(size_t)(bcol + wid * 16 + srow) * K + kb + skof], &Bs[cur][wid * 16][0]);
  };

  stg(0, 0);
  __syncthreads();
  int cur = 0;
  const int nk32 = K >> 5;
  for (int kt = 0; kt < nk32; ++kt) {
    if (kt + 1 < nk32) stg((kt + 1) << 5, cur ^ 1);
    bf16x8 af[4], bfr[2];
#pragma unroll
    for (int m = 0; m < 4; ++m) af[m] = *(const bf16x8*)&As[cur][wr * 64 + m * 16 + fr][fg * 8];
#pragma unroll
    for (int n = 0; n < 2; ++n) bfr[n] = *(const bf16x8*)&Bs[cur][wc * 32 + n * 16 + fr][fg * 8];
#pragma unroll
    for (int m = 0; m < 4; ++m)
#pragma unroll
      for (int n = 0; n < 2; ++n) acc[m][n] = mfma16(af[m], bfr[n], acc[m][n]);
    __syncthreads();
    cur ^= 1;
  }

#pragma unroll
  for (int m = 0; m < 4; ++m)
#pragma unroll
    for (int n = 0; n < 2; ++n)
#pragma unroll
      for (int r = 0; r < 4; ++r) {
        const int row = brow + wr * 64 + m * 16 + fg * 4 + r;
        const int col = bcol + wc * 32 + n * 16 + fr;
        const size_t o = (size_t)row * N + col;
        const float v = acc[m][n][r] + bias[col];
        if (EPI == 3) outf[o] = v + res[o];
        else if (EPI == 4) outf[o] = v;
        else outf[o] = (1.0f + v) * q2[o] + outf[o];
      }
}

// ---------------- 128x64-tile split-K=2 GEMM, BK=32, bf16 partial sums -------------
__global__ __launch_bounds__(256) void gemm64b(const u16* __restrict__ A, const u16* __restrict__ Bt,
                                               int N, int K, u16* __restrict__ sk0, u16* __restrict__ sk1,
                                               int nbx) {
  __shared__ u16 As[2][128][32];
  __shared__ u16 Bs[2][64][32];
  const int wg = swz8(blockIdx.x, gridDim.x);
  const int brow = (wg / nbx) * 128, bcol = (wg % nbx) * 64;
  const int kper = K >> 1;
  const int k0 = blockIdx.y * kper;
  const int l = threadIdx.x & 63, wid = threadIdx.x >> 6;
  const int wr = wid >> 1, wc = wid & 1, fr = l & 15, fg = l >> 4;
  const int srow = l >> 2, skof = (l & 3) << 3;

  f32x4 acc[4][2];
#pragma unroll
  for (int m = 0; m < 4; ++m)
#pragma unroll
    for (int n = 0; n < 2; ++n) acc[m][n] = (f32x4){0.f, 0.f, 0.f, 0.f};

  auto stg = [&](int kb, int cur) {
    gload16(&A[(size_t)(brow + wid * 32 + srow) * K + kb + skof], &As[cur][wid * 32][0]);
    gload16(&A[(size_t)(brow + wid * 32 + 16 + srow) * K + kb + skof], &As[cur][wid * 32 + 16][0]);
    gload16(&Bt[(size_t)(bcol + wid * 16 + srow) * K + kb + skof], &Bs[cur][wid * 16][0]);
  };

  stg(k0, 0);
  __syncthreads();
  int cur = 0;
  const int nk32 = kper >> 5;
  for (int kt = 0; kt < nk32; ++kt) {
    if (kt + 1 < nk32) stg(k0 + ((kt + 1) << 5), cur ^ 1);
    bf16x8 af[4], bfr[2];
#pragma unroll
    for (int m = 0; m < 4; ++m) af[m] = *(const bf16x8*)&As[cur][wr * 64 + m * 16 + fr][fg * 8];
#pragma unroll
    for (int n = 0; n < 2; ++n) bfr[n] = *(const bf16x8*)&Bs[cur][wc * 32 + n * 16 + fr][fg * 8];
#pragma unroll
    for (int m = 0; m < 4; ++m)
#pragma unroll
      for (int n = 0; n < 2; ++n) acc[m][n] = mfma16(af[m], bfr[n], acc[m][n]);
    __syncthreads();
    cur ^= 1;
  }

  u16* out = blockIdx.y ? sk1 : sk0;
#pragma unroll
  for (int m = 0; m < 4; ++m)
#pragma unroll
    for (int n = 0; n < 2; ++n)
#pragma unroll
      for (int r = 0; r < 4; ++r) {
        const int row = brow + wr * 64 + m * 16 + fg * 4 + r;
        const int col = bcol + wc * 32 + n * 16 + fr;
        out[(size_t)row * N + col] = f2bf(acc[m][n][r]);
      }
}

// ---------------- CA grouped GEMM -------------
__global__ __launch_bounds__(256) void gemm3_k(const u16* A0, const u16* A1, const u16* A2,
                                               const u16* B0, const u16* B1, const u16* B2,
                                               u16* O0, u16* O1, u16* O2) {
  const int z = blockIdx.y;
  const int wg = swz8(blockIdx.x, gridDim.x);
  const int bx = wg & 7, by = wg >> 3;
  if (z > 0 && by >= 16) return;
  const u16* A = z == 0 ? A0 : (z == 1 ? A1 : A2);
  const u16* Bt = z == 0 ? B0 : (z == 1 ? B1 : B2);
  u16* O = z == 0 ? O0 : (z == 1 ? O1 : O2);
  __shared__ u16 As[2][128][32];
  __shared__ u16 Bs[2][128][32];
  const int brow = by * 128, bcol = bx * 128;
  const int l = threadIdx.x & 63, wid = threadIdx.x >> 6;
  const int wr = wid >> 1, wc = wid & 1, fr = l & 15, fg = l >> 4;
  f32x4 acc[4][4];
#pragma unroll
  for (int m = 0; m < 4; ++m)
#pragma unroll
    for (int n = 0; n < 4; ++n) acc[m][n] = (f32x4){0.f, 0.f, 0.f, 0.f};
  gcore(A, Bt, 1024, brow, bcol, 0, 32, As, Bs, acc);
#pragma unroll
  for (int m = 0; m < 4; ++m)
#pragma unroll
    for (int n = 0; n < 4; ++n)
#pragma unroll
      for (int r = 0; r < 4; ++r) {
        const int row = brow + wr * 64 + m * 16 + fg * 4 + r;
        const int col = bcol + wc * 64 + n * 16 + fr;
        O[(size_t)row * 1024 + col] = f2bf(acc[m][n][r]);
      }
}

// ---------------- flash attention: shared dbuf K/V staging (R14) -------------
template <int QDIV, int PDIV>
__global__ __launch_bounds__(256) void attn_k(const u16* __restrict__ QH, const u16* __restrict__ KH,
                                              const u16* __restrict__ VT, u16* __restrict__ AO,
                                              const int* __restrict__ pmask, const float* __restrict__ Mrow,
                                              int Nq, int Nk, int qs, int ks) {
  __shared__ u16 KS[2][2048];
  __shared__ u16 VS[2][2048];
  __shared__ u16 PL[4][16][40];
  const int tid = threadIdx.x;
  const int l = tid & 63, wid = tid >> 6;
  const int fr = l & 15, fg = l >> 4;
  const int nqb = Nq >> 6;
  const int wgid = swz8(blockIdx.x, gridDim.x);
  const int qb = wgid % nqb;
  const int bh = wgid / nqb;
  const int h = bh & 15, b = bh >> 4;
  const int q0 = qb * 64 + wid * 16;

  u16 (*Pl)[40] = PL[wid];

  const int krow = l >> 3;
  const int kslot = (l & 7) ^ krow;
  const int vrow = l >> 2;
  const int vslot = (l & 3) ^ (vrow & 3);

  const size_t qrow = (size_t)(b * Nq + q0 + fr) * qs + h * 64;
  const bf16x8 aq0 = *(const bf16x8*)&QH[qrow + fg * 8];
  const bf16x8 aq1 = *(const bf16x8*)&QH[qrow + 32 + fg * 8];

  float Mr[4];
#pragma unroll
  for (int r = 0; r < 4; ++r) Mr[r] = Mrow[b * Tt + ((q0 + fg * 4 + r) >> 1)];

  f32x4 o[4];
#pragma unroll
  for (int c = 0; c < 4; ++c) o[c] = (f32x4){0.f, 0.f, 0.f, 0.f};
  float lsum[4] = {0.f, 0.f, 0.f, 0.f};

  int nkt = Nk >> 5;
  if (Mrow[b * Tt + ((qb * 64) >> 1)] == 0.0f) {
    const int kallow = (qb * 64 + 63) / QDIV + 1;
    const int t = (kallow + 31) >> 5;
    if (t < nkt) nkt = t;
  }

  const int sw0 = (fg ^ (fr & 7)) * 8;
  const int sw1 = ((4 + fg) ^ (fr & 7)) * 8;
  const size_t vtb = (size_t)b * 1024 * Nk + (size_t)(h * 64) * Nk;

  auto stage = [&](int kb, int buf) {
    gload16(&KH[(size_t)(b * Nk + kb + wid * 8 + krow) * ks + h * 64 + kslot * 8], &KS[buf][wid * 512]);
    gload16(&VT[vtb + (size_t)(wid * 16 + vrow) * Nk + kb + vslot * 8], &VS[buf][wid * 512]);
  };

  stage(0, 0);
  __syncthreads();
  int buf = 0;

  for (int kt = 0; kt < nkt; ++kt) {
    const int kb = kt << 5;
    if (kt + 1 < nkt) stage((kt + 1) << 5, buf ^ 1);

    const u16* Ksl = KS[buf];
    const u16* Vsl = VS[buf];

    f32x4 s0 = (f32x4){0.f, 0.f, 0.f, 0.f}, s1 = (f32x4){0.f, 0.f, 0.f, 0.f};
    {
      bf16x8 kf;
      kf = *(const bf16x8*)&Ksl[fr * 64 + sw0];        s0 = mfma16(aq0, kf, s0);
      kf = *(const bf16x8*)&Ksl[fr * 64 + sw1];        s0 = mfma16(aq1, kf, s0);
      kf = *(const bf16x8*)&Ksl[(16 + fr) * 64 + sw0]; s1 = mfma16(aq0, kf, s1);
      kf = *(const bf16x8*)&Ksl[(16 + fr) * 64 + sw1]; s1 = mfma16(aq1, kf, s1);
    }
    const int c0 = kb + fr, c1 = kb + 16 + fr;
    const float pad0 = pmask[b * Tt + (PDIV == 2 ? (c0 >> 1) : c0)] ? NEGV : 0.0f;
    const float pad1 = pmask[b * Tt + (PDIV == 2 ? (c1 >> 1) : c1)] ? NEGV : 0.0f;

#pragma unroll
    for (int r = 0; r < 4; ++r) {
      const int rq = (q0 + fg * 4 + r) >> (QDIV == 2 ? 1 : 0);
      float v0 = s0[r] * 0.125f; v0 = (c0 <= rq) ? v0 : NEGV; v0 += pad0;
      float v1 = s1[r] * 0.125f; v1 = (c1 <= rq) ? v1 : NEGV; v1 += pad1;
      const float p0 = __expf(v0 - Mr[r]);
      const float p1 = __expf(v1 - Mr[r]);
      lsum[r] += p0 + p1;
      Pl[fg * 4 + r][fr] = f2bf(p0);
      Pl[fg * 4 + r][16 + fr] = f2bf(p1);
    }

    const bf16x8 pa = *(const bf16x8*)&Pl[fr][fg * 8];
#pragma unroll
    for (int c = 0; c < 4; ++c) {
      const bf16x8 vb = *(const bf16x8*)&Vsl[(c * 16 + fr) * 32 + ((fg ^ (fr & 3)) << 3)];
      o[c] = mfma16(pa, vb, o[c]);
    }
    __syncthreads();
    buf ^= 1;
  }

#pragma unroll
  for (int r = 0; r < 4; ++r) {
    lsum[r] += __shfl_xor(lsum[r], 1);
    lsum[r] += __shfl_xor(lsum[r], 2);
    lsum[r] += __shfl_xor(lsum[r], 4);
    lsum[r] += __shfl_xor(lsum[r], 8);
  }

#pragma unroll
  for (int c = 0; c < 4; ++c)
#pragma unroll
    for (int r = 0; r < 4; ++r) {
      const int row = q0 + fg * 4 + r;
      AO[(size_t)(b * Nq + row) * Dd + h * 64 + c * 16 + fr] = f2bf(o[c][r] / lsum[r]);
    }
}

// =======================================================================================
extern "C" void kernel_launch(void* const* d_in, const int* in_sizes, int n_in,
                              void* d_out, int out_size, void* d_ws, size_t ws_size,
                              hipStream_t stream) {
  (void)in_sizes; (void)n_in; (void)out_size; (void)ws_size;
  const float* q_in   = (const float*)d_in[0];
  const float* c_in   = (const float*)d_in[1];
  const float* pe     = (const float*)d_in[2];
  const int*   pmask  = (const int*)d_in[3];
  const float* w_mod  = (const float*)d_in[4];
  const float* b_mod  = (const float*)d_in[5];
  const float* sa_wq  = (const float*)d_in[6];
  const float* sa_wk  = (const float*)d_in[7];
  const float* sa_wv  = (const float*)d_in[8];
  const float* sa_wo  = (const float*)d_in[9];
  const float* sa_bo  = (const float*)d_in[10];
  const float* ca_wq  = (const float*)d_in[11];
  const float* ca_wk  = (const float*)d_in[12];
  const float* ca_wv  = (const float*)d_in[13];
  const float* ca_wo  = (const float*)d_in[14];
  const float* ca_bo  = (const float*)d_in[15];
  const float* gk     = (const float*)d_in[16];
  const float* bk     = (const float*)d_in[17];
  const float* gv     = (const float*)d_in[18];
  const float* bv     = (const float*)d_in[19];
  const float* w_alpha= (const float*)d_in[20];
  const float* b_alpha= (const float*)d_in[21];
  const float* w1     = (const float*)d_in[22];
  const float* b1     = (const float*)d_in[23];
  const float* w2     = (const float*)d_in[24];
  const float* b2     = (const float*)d_in[25];

  // ---- workspace layout (u16 element offsets) ----
  u16* ws = (u16*)d_ws;
  u16* WMODt  = ws + 0;                     // [6144][1024]; dead after mod GEMM
  float* Mp   = (float*)(ws + 4194304);     // [4][512] overlay in dead WMODt tail
  u16* SK1b   = WMODt;                      // MLP2 split-1 (dead WMODt head)
  u16* SAWQt  = ws + 6291456;
  u16* SAWKt  = ws + 7340032;
  u16* SAWVt  = ws + 8388608;
  u16* SAWOt  = ws + 9437184;
  u16* CAWQt  = ws + 10485760;
  u16* CAWKt  = ws + 11534336;
  u16* CAWVt  = ws + 12582912;
  u16* CAWOt  = ws + 13631488;
  u16* WALPHt = ws + 14680064;
  u16* W1t    = ws + 16777216;
  u16* W2t    = ws + 20971520;
  u16* Xs     = ws + 25165824;              // silu(c); dead after mod GEMM
  u16* KINp   = Xs;
  u16* VINp   = SAWQt;
  u16* MODbf  = ws + 27262976;              // [2048][6144]
  u16* LNO    = ws + 39845888;
  u16* SK0b   = LNO;                        // MLP2 split-0 (LNO dead after MLP1)
  u16* BIG    = ws + 44040192;
  u16* QKVp = BIG;
  u16* VTsa = BIG + 12582912;
  u16* AOp  = LNO;
  u16* CAQp = BIG;
  u16* CAKp = BIG + 4194304;
  u16* CAVp = BIG + 6291456;
  u16* VT2  = BIG + 8388608;
  u16* AO2p = BIG + 10485760;
  u16* CATp = BIG;
  u16* HBp  = BIG;
  float* Qres = (float*)(ws + 60817408);
  float* Q2f  = Qres + 4194304;
  float* outp = (float*)d_out;

  const dim3 blk(256);

  // ---- all 12 weight transposes in ONE launch ----
  TrPack pk;
  int off = 0;
  auto add = [&](int i, const float* s, u16* d, int R, int C) {
    pk.t[i].s = s; pk.t[i].d = d; pk.t[i].R = R; pk.t[i].C = C; pk.t[i].t0 = off;
    off += (C >> 5) * (R >> 5);
  };
  add(0, w_mod, WMODt, 1024, 6144);
  add(1, sa_wq, SAWQt, 1024, 1024);
  add(2, sa_wk, SAWKt, 1024, 1024);
  add(3, sa_wv, SAWVt, 1024, 1024);
  add(4, sa_wo, SAWOt, 1024, 1024);
  add(5, ca_wq, CAWQt, 1024, 1024);
  add(6, ca_wk, CAWKt, 1024, 1024);
  add(7, ca_wv, CAWVt, 1024, 1024);
  add(8, ca_wo, CAWOt, 1024, 1024);
  add(9, w_alpha, WALPHt, 2048, 1024);
  add(10, w1, W1t, 1024, 4096);
  add(11, w2, W2t, 4096, 1024);
  tr_all<<<off, dim3(32, 8), 0, stream>>>(pk);

  // modulation
  silu_k<<<8192, blk, 0, stream>>>(c_in, Xs, 2048 * 1024);
  gemm_k<1><<<768, blk, 0, stream>>>(Xs, WMODt, 6144, 1024, b_mod, MODbf, 48);
  mrow_k<<<1, 64, 0, stream>>>(pmask, Mp);

  // ---- self-attention ----
  ln_mod_k<<<4096, blk, 0, stream>>>(q_in, MODbf, LNO, 0);
  gemm_k<0><<<768, blk, 0, stream>>>(LNO, SAWQt, 3072, 1024, nullptr, QKVp, 24);
  tr16_k<<<dim3(32, 128), dim3(32, 8), 0, stream>>>(QKVp + 2048, VTsa, 3072, 1024);
  ln_kv_k<<<2048, blk, 0, stream>>>(c_in, pe, gk, bk, gv, bv, KINp, VINp);
  attn_k<1, 2><<<1024, blk, 0, stream>>>(QKVp, QKVp + 1024, VTsa, AOp, pmask, Mp,
                                         1024, 1024, 3072, 3072);
  gemm64<3><<<512, blk, 0, stream>>>(AOp, SAWOt, 1024, 1024, sa_bo, q_in, nullptr, Qres, 16);

  // ---- cross-attention ----
  ln_mod_k<<<4096, blk, 0, stream>>>(Qres, MODbf, LNO, 2);
  gemm3_k<<<dim3(256, 3), blk, 0, stream>>>(LNO, KINp, VINp, CAWQt, CAWKt, CAWVt, CAQp, CAKp, CAVp);
  tr16_k<<<dim3(32, 64), dim3(32, 8), 0, stream>>>(CAVp, VT2, 1024, 512);
  attn_k<2, 1><<<1024, blk, 0, stream>>>(CAQp, CAKp, VT2, AO2p, pmask, Mp,
                                         1024, 512, 1024, 1024);
  gemm64<4><<<512, blk, 0, stream>>>(AO2p, CAWOt, 1024, 1024, ca_bo, nullptr, nullptr, Q2f, 16);
  cat_k<<<16384, blk, 0, stream>>>(Q2f, Qres, CATp);
  gemm64<5><<<512, blk, 0, stream>>>(CATp, WALPHt, 1024, 2048, b_alpha, nullptr, Q2f, Qres, 16);

  // ---- MLP ----
  ln_mod_k<<<4096, blk, 0, stream>>>(Qres, MODbf, LNO, 4);
  gemm_k<2><<<1024, blk, 0, stream>>>(LNO, W1t, 4096, 1024, b1, HBp, 32);
  gemm64b<<<dim3(512, 2), blk, 0, stream>>>(HBp, W2t, 1024, 4096, SK0b, SK1b, 16);
  red2_k<<<4096, blk, 0, stream>>>(SK0b, SK1b, b2, Qres, outp);
}